// Round 8
// baseline (362.032 us; speedup 1.0000x reference)
//
#include <hip/hip_runtime.h>

#define NN 100000
#define NE 1000000
#define BSH 9        // sort bucket: 512 cols
#define BCOLS 512
#define NBUCK 196    // ceil(NN/512)
#define SBLK 64      // hist/scatter edge-partition blocks (coarse runs: ~80 edges)
#define STHR 512
#define QCOLS 128    // agg quarter-bucket cols
#define NQ (NBUCK * 4)   // 784 agg blocks
#define CAP_Q 2048   // max matched edges per quarter (mean ~1280, >20 sigma)
#define YSTRIDE 32   // y row: 21 floats + pad -> 128 B

// ---------------------------------------------------------------------------
// K_f: fuse linear chain into Mt[128][24]:
//   Mt[k][0..20] = fused GCN->layer1 column k ([Wu@W1_top; Wm@W1_bot])
//   Mt[k][21]    = b1'[k],  Mt[k][22] = W2[k],  Mt[k][23] = pad
// Row = 96 B = 6 float4s.
// ---------------------------------------------------------------------------
__global__ __launch_bounds__(128) void fuse_kernel(const float* __restrict__ Wu,
                                                   const float* __restrict__ bu,
                                                   const float* __restrict__ Wm,
                                                   const float* __restrict__ bm,
                                                   const float* __restrict__ W1,
                                                   const float* __restrict__ b1,
                                                   const float* __restrict__ W2,
                                                   float* __restrict__ Mt) {
    const int j = threadIdx.x;
    float w1c[128];
#pragma unroll
    for (int k = 0; k < 128; k++) w1c[k] = W1[k * 128 + j];

    float* row = Mt + j * 24;
#pragma unroll
    for (int m = 0; m < 3; m++) {
        float acc = 0.f;
#pragma unroll
        for (int k = 0; k < 64; k++) acc = fmaf(Wu[m * 64 + k], w1c[k], acc);
        row[m] = acc;
    }
#pragma unroll
    for (int m = 0; m < 18; m++) {
        float acc = 0.f;
#pragma unroll
        for (int k = 0; k < 64; k++) acc = fmaf(Wm[m * 64 + k], w1c[64 + k], acc);
        row[3 + m] = acc;
    }
    float bp = b1[j];
#pragma unroll
    for (int k = 0; k < 64; k++) {
        bp = fmaf(bu[k], w1c[k], bp);
        bp = fmaf(bm[k], w1c[64 + k], bp);
    }
    row[21] = bp;
    row[22] = W2[j];
    row[23] = 0.f;
}

// ---------------------------------------------------------------------------
// K_a: per-(block,bucket) histogram into LDS; H[b*SBLK+blk]. No global atomics.
// ---------------------------------------------------------------------------
__global__ __launch_bounds__(STHR) void bhist_kernel(const int* __restrict__ col,
                                                     int* __restrict__ H) {
    __shared__ int h[NBUCK];
    for (int i = threadIdx.x; i < NBUCK; i += STHR) h[i] = 0;
    __syncthreads();
    for (int e = blockIdx.x * STHR + threadIdx.x; e < NE; e += SBLK * STHR)
        atomicAdd(&h[col[e] >> BSH], 1);
    __syncthreads();
    for (int b = threadIdx.x; b < NBUCK; b += STHR)
        H[b * SBLK + blockIdx.x] = h[b];
}

// ---------------------------------------------------------------------------
// K_b: exclusive scan of H (NBUCK*SBLK = 12544 ints) in one block.
// ---------------------------------------------------------------------------
__global__ __launch_bounds__(1024) void bscan_kernel(int* __restrict__ H) {
    const int TOT = NBUCK * SBLK;          // 12544
    const int PER = 13;                    // 1024*13 >= TOT
    const int t = threadIdx.x;
    const int base = t * PER;
    int v[PER];
    int sum = 0;
#pragma unroll
    for (int i = 0; i < PER; i++) {
        int idx = base + i;
        v[i] = (idx < TOT) ? H[idx] : 0;
        sum += v[i];
    }
    __shared__ int s[1024];
    s[t] = sum;
    __syncthreads();
    for (int off = 1; off < 1024; off <<= 1) {
        int x = (t >= off) ? s[t - off] : 0;
        __syncthreads();
        s[t] += x;
        __syncthreads();
    }
    int run = s[t] - sum;
#pragma unroll
    for (int i = 0; i < PER; i++) {
        int idx = base + i;
        if (idx < TOT) H[idx] = run;
        run += v[i];
    }
}

// ---------------------------------------------------------------------------
// K_c: deterministic scatter into per-(bucket,block) runs (~640 B each).
// Payload: x = (col&511) | (row<<9), y = ew bits. No global atomics.
// ---------------------------------------------------------------------------
__global__ __launch_bounds__(STHR) void bscatter_kernel(const int* __restrict__ ei,
                                                        const float* __restrict__ ew,
                                                        const int* __restrict__ H,
                                                        int2* __restrict__ mid) {
    __shared__ int rbase[NBUCK];
    __shared__ int rcnt[NBUCK];
    for (int i = threadIdx.x; i < NBUCK; i += STHR) {
        rbase[i] = H[i * SBLK + blockIdx.x];
        rcnt[i] = 0;
    }
    __syncthreads();
    for (int e = blockIdx.x * STHR + threadIdx.x; e < NE; e += SBLK * STHR) {
        const int c = ei[NE + e];
        const int r = ei[e];
        const float w = ew[e];
        const int b = c >> BSH;
        const int pos = rbase[b] + atomicAdd(&rcnt[b], 1);
        mid[pos] = make_int2((c & (BCOLS - 1)) | (r << BSH), __float_as_int(w));
    }
}

// ---------------------------------------------------------------------------
// K_d: per-bucket degree -> dinv AND pack y[c][0..20] = dinv[c]*[ux_c, mx_c]
// into 128-B-aligned rows.
// ---------------------------------------------------------------------------
__global__ __launch_bounds__(BCOLS) void bdeg_y_kernel(const int2* __restrict__ mid,
                                                       const int* __restrict__ H,
                                                       const float* __restrict__ ux,
                                                       const float* __restrict__ mx,
                                                       float* __restrict__ dinv,
                                                       float* __restrict__ y) {
    __shared__ float dl[BCOLS];
    const int b = blockIdx.x;
    const int t = threadIdx.x;
    dl[t] = 0.f;
    __syncthreads();
    const int start = H[b * SBLK];
    const int end = (b + 1 < NBUCK) ? H[(b + 1) * SBLK] : NE;
    for (int i = start + t; i < end; i += BCOLS) {
        const int2 p = mid[i];
        atomicAdd(&dl[p.x & (BCOLS - 1)], __int_as_float(p.y));
    }
    __syncthreads();
    const int c = b * BCOLS + t;
    if (c < NN) {
        const float dc = rsqrtf(dl[t] + 1.0f);
        dinv[c] = dc;
        float yr[21];
        const float* uc = ux + (size_t)c * 3;
        const float* mc = mx + (size_t)c * 18;
        yr[0] = dc * uc[0];
        yr[1] = dc * uc[1];
        yr[2] = dc * uc[2];
#pragma unroll
        for (int k = 0; k < 18; k++) yr[3 + k] = dc * mc[k];
        float* yo = y + (size_t)c * YSTRIDE;
#pragma unroll
        for (int q = 0; q < 5; q++)
            ((float4*)yo)[q] = make_float4(yr[4 * q], yr[4 * q + 1],
                                           yr[4 * q + 2], yr[4 * q + 3]);
        yo[20] = yr[20];
    }
}

// ---------------------------------------------------------------------------
// K_e: quarter-bucket agg + MLP. Block = bucket quarter (128 cols, 512 thr):
// filter+count+permute the bucket segment for own cols, then 4 adjacent
// lanes per col walk edges (stride 4, 2-edge batches), combine via shfl_xor,
// MLP split 32 hidden units per sub-lane, shfl-reduce, write.
// ---------------------------------------------------------------------------
__global__ __launch_bounds__(512, 6) void bagg_mlp_kernel(const int2* __restrict__ mid,
                                                          const int* __restrict__ H,
                                                          const float* __restrict__ dinv,
                                                          const float* __restrict__ y,
                                                          const float* __restrict__ Mt,
                                                          const float* __restrict__ b2,
                                                          float* __restrict__ out) {
    __shared__ unsigned short idx16[CAP_Q];   // 4 KB
    __shared__ int cbase[QCOLS + 1];
    __shared__ int ccur[QCOLS];
    __shared__ int ovf;

    const int blk = blockIdx.x;
    const int b = blk >> 2;                   // bucket
    const int q = blk & 3;                    // quarter
    const int t = threadIdx.x;
    const int lc = t >> 2;                    // local col 0..127
    const int sub = t & 3;                    // 4 lanes per col (adjacent)

    const int start = H[b * SBLK];
    const int end = (b + 1 < NBUCK) ? H[(b + 1) * SBLK] : NE;
    const int seg = end - start;

    // phase 1: counts for own quarter
    if (t < QCOLS) ccur[t] = 0;
    if (t == 0) ovf = 0;
    __syncthreads();
    for (int i = t; i < seg; i += 512) {
        const int cl = mid[start + i].x & (BCOLS - 1);
        if ((cl >> 7) == q) atomicAdd(&ccur[cl & (QCOLS - 1)], 1);
    }
    __syncthreads();

    // phase 2: exclusive scan of 128 counts
    int myc = 0;
    if (t < QCOLS) { myc = ccur[t]; cbase[t] = myc; }
    __syncthreads();
    for (int off = 1; off < QCOLS; off <<= 1) {
        int x = 0;
        if (t < QCOLS && t >= off) x = cbase[t - off];
        __syncthreads();
        if (t < QCOLS) cbase[t] += x;
        __syncthreads();
    }
    int incl = (t < QCOLS) ? cbase[t] : 0;
    __syncthreads();
    if (t < QCOLS) {
        cbase[t] = incl - myc;
        ccur[t] = incl - myc;
        if (t == QCOLS - 1) {
            cbase[QCOLS] = incl;
            if (incl > CAP_Q) ovf = 1;
        }
    }
    __syncthreads();

    float s21[21];
#pragma unroll
    for (int m = 0; m < 21; m++) s21[m] = 0.f;

    if (!ovf) {
        // phase 3: build permutation (own quarter only)
        for (int i = t; i < seg; i += 512) {
            const int cl = mid[start + i].x & (BCOLS - 1);
            if ((cl >> 7) == q) {
                const int pos = atomicAdd(&ccur[cl & (QCOLS - 1)], 1);
                idx16[pos] = (unsigned short)i;
            }
        }
        __syncthreads();

        // phase 4: walk own col, stride 4, 2-edge batches for MLP overlap
        const int s1 = cbase[lc + 1];
        int i = cbase[lc] + sub;
        while (i < s1) {
            const int ia = idx16[i];
            const bool has2 = (i + 4 < s1);
            const int ib = has2 ? idx16[i + 4] : ia;
            const int2 pa = mid[start + ia];
            const int2 pb = mid[start + ib];
            const float wa = __int_as_float(pa.y);
            const float wb = has2 ? __int_as_float(pb.y) : 0.f;
            const float* ya = y + (size_t)(((unsigned)pa.x) >> BSH) * YSTRIDE;
            const float* yb = y + (size_t)(((unsigned)pb.x) >> BSH) * YSTRIDE;
            const float4 a0 = ((const float4*)ya)[0];
            const float4 a1 = ((const float4*)ya)[1];
            const float4 a2 = ((const float4*)ya)[2];
            const float4 a3 = ((const float4*)ya)[3];
            const float4 a4 = ((const float4*)ya)[4];
            const float a20 = ya[20];
            const float4 c0 = ((const float4*)yb)[0];
            const float4 c1 = ((const float4*)yb)[1];
            const float4 c2 = ((const float4*)yb)[2];
            const float4 c3 = ((const float4*)yb)[3];
            const float4 c4 = ((const float4*)yb)[4];
            const float c20 = yb[20];
            s21[0]  = fmaf(wa, a0.x, s21[0]);  s21[1]  = fmaf(wa, a0.y, s21[1]);
            s21[2]  = fmaf(wa, a0.z, s21[2]);  s21[3]  = fmaf(wa, a0.w, s21[3]);
            s21[4]  = fmaf(wa, a1.x, s21[4]);  s21[5]  = fmaf(wa, a1.y, s21[5]);
            s21[6]  = fmaf(wa, a1.z, s21[6]);  s21[7]  = fmaf(wa, a1.w, s21[7]);
            s21[8]  = fmaf(wa, a2.x, s21[8]);  s21[9]  = fmaf(wa, a2.y, s21[9]);
            s21[10] = fmaf(wa, a2.z, s21[10]); s21[11] = fmaf(wa, a2.w, s21[11]);
            s21[12] = fmaf(wa, a3.x, s21[12]); s21[13] = fmaf(wa, a3.y, s21[13]);
            s21[14] = fmaf(wa, a3.z, s21[14]); s21[15] = fmaf(wa, a3.w, s21[15]);
            s21[16] = fmaf(wa, a4.x, s21[16]); s21[17] = fmaf(wa, a4.y, s21[17]);
            s21[18] = fmaf(wa, a4.z, s21[18]); s21[19] = fmaf(wa, a4.w, s21[19]);
            s21[20] = fmaf(wa, a20,  s21[20]);
            s21[0]  = fmaf(wb, c0.x, s21[0]);  s21[1]  = fmaf(wb, c0.y, s21[1]);
            s21[2]  = fmaf(wb, c0.z, s21[2]);  s21[3]  = fmaf(wb, c0.w, s21[3]);
            s21[4]  = fmaf(wb, c1.x, s21[4]);  s21[5]  = fmaf(wb, c1.y, s21[5]);
            s21[6]  = fmaf(wb, c1.z, s21[6]);  s21[7]  = fmaf(wb, c1.w, s21[7]);
            s21[8]  = fmaf(wb, c2.x, s21[8]);  s21[9]  = fmaf(wb, c2.y, s21[9]);
            s21[10] = fmaf(wb, c2.z, s21[10]); s21[11] = fmaf(wb, c2.w, s21[11]);
            s21[12] = fmaf(wb, c3.x, s21[12]); s21[13] = fmaf(wb, c3.y, s21[13]);
            s21[14] = fmaf(wb, c3.z, s21[14]); s21[15] = fmaf(wb, c3.w, s21[15]);
            s21[16] = fmaf(wb, c4.x, s21[16]); s21[17] = fmaf(wb, c4.y, s21[17]);
            s21[18] = fmaf(wb, c4.z, s21[18]); s21[19] = fmaf(wb, c4.w, s21[19]);
            s21[20] = fmaf(wb, c20,  s21[20]);
            i += 8;
        }
    } else {
        // fallback (seg quarter > CAP_Q; statistically never): direct scan
        const int mycl = (q << 7) | lc;
        for (int i = sub; i < seg; i += 4) {
            const int2 p = mid[start + i];
            if ((p.x & (BCOLS - 1)) == mycl) {
                const float w = __int_as_float(p.y);
                const float* yr = y + (size_t)(((unsigned)p.x) >> BSH) * YSTRIDE;
#pragma unroll
                for (int m = 0; m < 21; m++) s21[m] = fmaf(w, yr[m], s21[m]);
            }
        }
    }

    // combine 4 partials (adjacent lanes) in-register
#pragma unroll
    for (int m = 0; m < 21; m++) {
        s21[m] += __shfl_xor(s21[m], 1);
        s21[m] += __shfl_xor(s21[m], 2);
    }

    const int c = b * BCOLS + (q << 7) + lc;
    if (c < NN) {
        // self-loop + dc scale (redundant on all 4 lanes; broadcast loads)
        const float dc = dinv[c];
        const float* yc = y + (size_t)c * YSTRIDE;
#pragma unroll
        for (int m = 0; m < 21; m++) s21[m] = dc * (s21[m] + yc[m]);

        // MLP: sub covers hidden units [sub*32, sub*32+32); rows as float4s
        float o = 0.f;
        const float* mb = Mt + sub * 32 * 24;
#pragma unroll 4
        for (int k = 0; k < 32; k++) {
            const float4* r4 = (const float4*)(mb + k * 24);
            const float4 r0 = r4[0], r1 = r4[1], r2 = r4[2];
            const float4 r3 = r4[3], r4v = r4[4], r5 = r4[5];
            float h = r5.y;                      // b1'
            h = fmaf(s21[0],  r0.x, h); h = fmaf(s21[1],  r0.y, h);
            h = fmaf(s21[2],  r0.z, h); h = fmaf(s21[3],  r0.w, h);
            h = fmaf(s21[4],  r1.x, h); h = fmaf(s21[5],  r1.y, h);
            h = fmaf(s21[6],  r1.z, h); h = fmaf(s21[7],  r1.w, h);
            h = fmaf(s21[8],  r2.x, h); h = fmaf(s21[9],  r2.y, h);
            h = fmaf(s21[10], r2.z, h); h = fmaf(s21[11], r2.w, h);
            h = fmaf(s21[12], r3.x, h); h = fmaf(s21[13], r3.y, h);
            h = fmaf(s21[14], r3.z, h); h = fmaf(s21[15], r3.w, h);
            h = fmaf(s21[16], r4v.x, h); h = fmaf(s21[17], r4v.y, h);
            h = fmaf(s21[18], r4v.z, h); h = fmaf(s21[19], r4v.w, h);
            h = fmaf(s21[20], r5.x, h);
            o = fmaf(fmaxf(h, 0.f), r5.z, o);    // * W2[k]
        }
        o += __shfl_xor(o, 1);
        o += __shfl_xor(o, 2);
        if (sub == 0) out[c] = o + b2[0];
    }
}

// ===========================================================================
extern "C" void kernel_launch(void* const* d_in, const int* in_sizes, int n_in,
                              void* d_out, int out_size, void* d_ws, size_t ws_size,
                              hipStream_t stream) {
    const float* ux = (const float*)d_in[0];   // user_x  [N,3]
    const float* mx = (const float*)d_in[1];   // movie_x [N,18]
    const int* ei = (const int*)d_in[2];       // edge_index [2,E]
    const float* ew = (const float*)d_in[3];   // edge_attr [E]
    const float* Wu = (const float*)d_in[4];   // [3,64]
    const float* bu = (const float*)d_in[5];   // [64]
    const float* Wm = (const float*)d_in[6];   // [18,64]
    const float* bm = (const float*)d_in[7];   // [64]
    const float* W1 = (const float*)d_in[8];   // [128,128]
    const float* b1 = (const float*)d_in[9];   // [128]
    const float* W2 = (const float*)d_in[10];  // [128,1]
    const float* b2 = (const float*)d_in[11];  // [1]
    float* out = (float*)d_out;

    char* ws = (char*)d_ws;
    float* dinv = (float*)ws;                        // 400,384 B (padded)
    int*   H    = (int*)(ws + 400384);               // 12544*4 = 50,176 B
    float* Mt   = (float*)(ws + 450560);             // 12,288 B (16-B aligned)
    float* y    = (float*)(ws + 462848);             // 128-B aligned; 12.8 MB
    int2*  mid  = (int2*)(ws + 462848 + (size_t)NN * YSTRIDE * 4);  // 8 MB
    // total ~21.3 MB

    fuse_kernel<<<1, 128, 0, stream>>>(Wu, bu, Wm, bm, W1, b1, W2, Mt);
    bhist_kernel<<<SBLK, STHR, 0, stream>>>(ei + NE, H);
    bscan_kernel<<<1, 1024, 0, stream>>>(H);
    bscatter_kernel<<<SBLK, STHR, 0, stream>>>(ei, ew, H, mid);
    bdeg_y_kernel<<<NBUCK, BCOLS, 0, stream>>>(mid, H, ux, mx, dinv, y);
    bagg_mlp_kernel<<<NQ, 512, 0, stream>>>(mid, H, dinv, y, Mt, b2, out);
}

// Round 9
// 255.555 us; speedup vs baseline: 1.4166x; 1.4166x over previous
//
#include <hip/hip_runtime.h>

#define NN 100000
#define NE 1000000
#define BSH 9        // sort bucket: 512 cols
#define BCOLS 512
#define NBUCK 196    // ceil(NN/512)
#define SBLK 64      // hist/scatter edge-partition blocks (runs ~80 edges / 640 B)
#define STHR 512
#define YSTRIDE 32   // y row: 21 floats + pad -> 128 B
#define AGB 1024     // bagg block threads

// ---------------------------------------------------------------------------
// K_f: fuse linear chain into Mt[128][24]:
//   Mt[k][0..20] = fused GCN->layer1 column k ([Wu@W1_top; Wm@W1_bot])
//   Mt[k][21]    = b1'[k],  Mt[k][22] = W2[k],  Mt[k][23] = pad
// ---------------------------------------------------------------------------
__global__ __launch_bounds__(128) void fuse_kernel(const float* __restrict__ Wu,
                                                   const float* __restrict__ bu,
                                                   const float* __restrict__ Wm,
                                                   const float* __restrict__ bm,
                                                   const float* __restrict__ W1,
                                                   const float* __restrict__ b1,
                                                   const float* __restrict__ W2,
                                                   float* __restrict__ Mt) {
    const int j = threadIdx.x;
    float w1c[128];
#pragma unroll
    for (int k = 0; k < 128; k++) w1c[k] = W1[k * 128 + j];

    float* row = Mt + j * 24;
#pragma unroll
    for (int m = 0; m < 3; m++) {
        float acc = 0.f;
#pragma unroll
        for (int k = 0; k < 64; k++) acc = fmaf(Wu[m * 64 + k], w1c[k], acc);
        row[m] = acc;
    }
#pragma unroll
    for (int m = 0; m < 18; m++) {
        float acc = 0.f;
#pragma unroll
        for (int k = 0; k < 64; k++) acc = fmaf(Wm[m * 64 + k], w1c[64 + k], acc);
        row[3 + m] = acc;
    }
    float bp = b1[j];
#pragma unroll
    for (int k = 0; k < 64; k++) {
        bp = fmaf(bu[k], w1c[k], bp);
        bp = fmaf(bm[k], w1c[64 + k], bp);
    }
    row[21] = bp;
    row[22] = W2[j];
    row[23] = 0.f;
}

// ---------------------------------------------------------------------------
// K_a: per-(block,bucket) histogram into LDS; H[b*SBLK+blk]. No global atomics.
// ---------------------------------------------------------------------------
__global__ __launch_bounds__(STHR) void bhist_kernel(const int* __restrict__ col,
                                                     int* __restrict__ H) {
    __shared__ int h[NBUCK];
    for (int i = threadIdx.x; i < NBUCK; i += STHR) h[i] = 0;
    __syncthreads();
    for (int e = blockIdx.x * STHR + threadIdx.x; e < NE; e += SBLK * STHR)
        atomicAdd(&h[col[e] >> BSH], 1);
    __syncthreads();
    for (int b = threadIdx.x; b < NBUCK; b += STHR)
        H[b * SBLK + blockIdx.x] = h[b];
}

// ---------------------------------------------------------------------------
// K_b: exclusive scan of H (NBUCK*SBLK = 12544 ints) in one block.
// ---------------------------------------------------------------------------
__global__ __launch_bounds__(1024) void bscan_kernel(int* __restrict__ H) {
    const int TOT = NBUCK * SBLK;          // 12544
    const int PER = 13;
    const int t = threadIdx.x;
    const int base = t * PER;
    int v[PER];
    int sum = 0;
#pragma unroll
    for (int i = 0; i < PER; i++) {
        int idx = base + i;
        v[i] = (idx < TOT) ? H[idx] : 0;
        sum += v[i];
    }
    __shared__ int s[1024];
    s[t] = sum;
    __syncthreads();
    for (int off = 1; off < 1024; off <<= 1) {
        int x = (t >= off) ? s[t - off] : 0;
        __syncthreads();
        s[t] += x;
        __syncthreads();
    }
    int run = s[t] - sum;
#pragma unroll
    for (int i = 0; i < PER; i++) {
        int idx = base + i;
        if (idx < TOT) H[idx] = run;
        run += v[i];
    }
}

// ---------------------------------------------------------------------------
// K_c: deterministic scatter into per-(bucket,block) runs (~640 B each).
// Payload: x = (col&511) | (row<<9), y = ew bits. No global atomics.
// ---------------------------------------------------------------------------
__global__ __launch_bounds__(STHR) void bscatter_kernel(const int* __restrict__ ei,
                                                        const float* __restrict__ ew,
                                                        const int* __restrict__ H,
                                                        int2* __restrict__ mid) {
    __shared__ int rbase[NBUCK];
    __shared__ int rcnt[NBUCK];
    for (int i = threadIdx.x; i < NBUCK; i += STHR) {
        rbase[i] = H[i * SBLK + blockIdx.x];
        rcnt[i] = 0;
    }
    __syncthreads();
    for (int e = blockIdx.x * STHR + threadIdx.x; e < NE; e += SBLK * STHR) {
        const int c = ei[NE + e];
        const int r = ei[e];
        const float w = ew[e];
        const int b = c >> BSH;
        const int pos = rbase[b] + atomicAdd(&rcnt[b], 1);
        mid[pos] = make_int2((c & (BCOLS - 1)) | (r << BSH), __float_as_int(w));
    }
}

// ---------------------------------------------------------------------------
// K_d: per-bucket degree -> dinv AND pack y[c][0..20] = dinv[c]*[ux_c, mx_c]
// into 128-B-aligned rows.
// ---------------------------------------------------------------------------
__global__ __launch_bounds__(BCOLS) void bdeg_y_kernel(const int2* __restrict__ mid,
                                                       const int* __restrict__ H,
                                                       const float* __restrict__ ux,
                                                       const float* __restrict__ mx,
                                                       float* __restrict__ dinv,
                                                       float* __restrict__ y) {
    __shared__ float dl[BCOLS];
    const int b = blockIdx.x;
    const int t = threadIdx.x;
    dl[t] = 0.f;
    __syncthreads();
    const int start = H[b * SBLK];
    const int end = (b + 1 < NBUCK) ? H[(b + 1) * SBLK] : NE;
    for (int i = start + t; i < end; i += BCOLS) {
        const int2 p = mid[i];
        atomicAdd(&dl[p.x & (BCOLS - 1)], __int_as_float(p.y));
    }
    __syncthreads();
    const int c = b * BCOLS + t;
    if (c < NN) {
        const float dc = rsqrtf(dl[t] + 1.0f);
        dinv[c] = dc;
        float yr[21];
        const float* uc = ux + (size_t)c * 3;
        const float* mc = mx + (size_t)c * 18;
        yr[0] = dc * uc[0];
        yr[1] = dc * uc[1];
        yr[2] = dc * uc[2];
#pragma unroll
        for (int k = 0; k < 18; k++) yr[3 + k] = dc * mc[k];
        float* yo = y + (size_t)c * YSTRIDE;
#pragma unroll
        for (int q = 0; q < 5; q++)
            ((float4*)yo)[q] = make_float4(yr[4 * q], yr[4 * q + 1],
                                           yr[4 * q + 2], yr[4 * q + 3]);
        yo[20] = yr[20];
    }
}

// ---------------------------------------------------------------------------
// K_e: half-bucket agg + MLP. Grid = 2 blocks per bucket (392 x 1024 thr).
// Each block: counting-sort the bucket's seg into its PRIVATE smid half
// (physically sorted (row,w) runs, L2-hot), then one WAVE per col walks the
// run as 3 edge-groups x 21 features (each y access = 21 contiguous floats,
// <=2 lines/group), software-pipelined. s21 -> LDS; MLP with wave-uniform
// scalar Mt loads.
// ---------------------------------------------------------------------------
__global__ __launch_bounds__(AGB) void bagg_mlp_kernel(const int2* __restrict__ mid,
                                                       const int* __restrict__ H,
                                                       const float* __restrict__ dinv,
                                                       const float* __restrict__ y,
                                                       const float* __restrict__ Mt,
                                                       const float* __restrict__ b2,
                                                       int2* __restrict__ smid,
                                                       float* __restrict__ out) {
    __shared__ int cbase[BCOLS + 1];
    __shared__ int ccur[BCOLS];
    __shared__ float sbuf[256 * 21];   // this half's s vectors (21.5 KB)
    __shared__ float obuf[256];

    const int blk = blockIdx.x;
    const int b = blk >> 1;
    const int half = blk & 1;
    const int t = threadIdx.x;
    const int start = H[b * SBLK];
    const int end = (b + 1 < NBUCK) ? H[(b + 1) * SBLK] : NE;
    const int seg = end - start;

    // phase 1: per-col counts
    if (t < BCOLS) ccur[t] = 0;
    __syncthreads();
    for (int i = t; i < seg; i += AGB)
        atomicAdd(&ccur[mid[start + i].x & (BCOLS - 1)], 1);
    __syncthreads();

    // phase 2: exclusive scan of 512 counts
    int myc = 0;
    if (t < BCOLS) { myc = ccur[t]; cbase[t] = myc; }
    __syncthreads();
    for (int off = 1; off < BCOLS; off <<= 1) {
        int x = 0;
        if (t < BCOLS && t >= off) x = cbase[t - off];
        __syncthreads();
        if (t < BCOLS) cbase[t] += x;
        __syncthreads();
    }
    if (t < BCOLS) {
        const int incl = cbase[t];
        cbase[t] = incl - myc;
        ccur[t] = incl - myc;
        if (t == BCOLS - 1) cbase[BCOLS] = incl;
    }
    __syncthreads();

    // phase 3: physically sort (row, w) into PRIVATE smid half
    int2* ms = smid + (size_t)half * NE;
    for (int i = t; i < seg; i += AGB) {
        const int2 p = mid[start + i];
        const int cl = p.x & (BCOLS - 1);
        const int pos = atomicAdd(&ccur[cl], 1);
        ms[start + pos] = make_int2((int)(((unsigned)p.x) >> BSH), p.y);
    }
    __syncthreads();

    // phase 4: one wave per col; 3 edge-groups x 21 features; pipelined
    const int wave = t >> 6;
    const int lane = t & 63;
    const int g = lane / 21;                  // 0..2 active, 3 = idle lane 63
    const int m = lane - g * 21;
    const bool active = (g < 3);
    const int lc0 = half * 256 + wave * 16;   // 16 cols per wave

    for (int j = 0; j < 16; j++) {
        const int lc = lc0 + j;
        const int s0 = cbase[lc];
        const int n = cbase[lc + 1] - s0;
        const int c = b * BCOLS + lc;
        const int2* run = ms + start + s0;

        float acc = 0.f;
        int i = 0;
        bool v = active && (g < n);
        int2 e = v ? run[g] : make_int2(0, 0);
        float yv = v ? y[((size_t)e.x << 5) + m] : 0.f;
        while (i < n) {
            const bool v2 = active && (i + 3 + g < n);
            const int2 e2 = v2 ? run[i + 3 + g] : e;     // prefetch edge
            const float w_ = v ? __int_as_float(e.y) : 0.f;
            acc = fmaf(w_, yv, acc);
            yv = v2 ? y[((size_t)e2.x << 5) + m] : 0.f;  // prefetch y
            e = e2;
            v = v2;
            i += 3;
        }
        // combine 3 group partials onto lanes 0..20
        const float a1 = __shfl(acc, m + 21);
        const float a2 = __shfl(acc, m + 42);
        if (lane < 21 && c < NN) {
            const float dc = dinv[c];
            const float tot = dc * (acc + a1 + a2 + y[((size_t)c << 5) + lane]);
            sbuf[(lc - half * 256) * 21 + lane] = tot;
        }
    }
    __syncthreads();

    // phase 5: MLP — threads 0..511; col = (t&255), k-half = t>>8.
    float o = 0.f;
    if (t < 512) {
        const int lq = t & 255;
        const int kh = t >> 8;
        float s21[21];
#pragma unroll
        for (int mm = 0; mm < 21; mm++) s21[mm] = sbuf[lq * 21 + mm];
        const float* mb = Mt + kh * 64 * 24;
#pragma unroll 4
        for (int k = 0; k < 64; k++) {
            const float* r = mb + k * 24;
            float h = r[21];
#pragma unroll
            for (int mm = 0; mm < 21; mm++) h = fmaf(s21[mm], r[mm], h);
            o = fmaf(fmaxf(h, 0.f), r[22], o);
        }
        if (kh == 1) obuf[lq] = o;
    }
    __syncthreads();
    if (t < 256) {
        const int c = b * BCOLS + half * 256 + t;
        if (c < NN) out[c] = o + obuf[t] + b2[0];
    }
}

// ===========================================================================
extern "C" void kernel_launch(void* const* d_in, const int* in_sizes, int n_in,
                              void* d_out, int out_size, void* d_ws, size_t ws_size,
                              hipStream_t stream) {
    const float* ux = (const float*)d_in[0];   // user_x  [N,3]
    const float* mx = (const float*)d_in[1];   // movie_x [N,18]
    const int* ei = (const int*)d_in[2];       // edge_index [2,E]
    const float* ew = (const float*)d_in[3];   // edge_attr [E]
    const float* Wu = (const float*)d_in[4];   // [3,64]
    const float* bu = (const float*)d_in[5];   // [64]
    const float* Wm = (const float*)d_in[6];   // [18,64]
    const float* bm = (const float*)d_in[7];   // [64]
    const float* W1 = (const float*)d_in[8];   // [128,128]
    const float* b1 = (const float*)d_in[9];   // [128]
    const float* W2 = (const float*)d_in[10];  // [128,1]
    const float* b2 = (const float*)d_in[11];  // [1]
    float* out = (float*)d_out;

    char* ws = (char*)d_ws;
    float* dinv = (float*)ws;                           // 400,384 B (padded)
    int*   H    = (int*)(ws + 400384);                  // 12544*4 = 50,176 B
    float* Mt   = (float*)(ws + 450560);                // 12,288 B
    float* y    = (float*)(ws + 462848);                // 128-B aligned; 12.8 MB
    int2*  mid  = (int2*)(ws + 462848 + (size_t)NN * YSTRIDE * 4);   // 8 MB
    int2*  smid = (int2*)(ws + 462848 + (size_t)NN * YSTRIDE * 4 + (size_t)NE * 8);
    // smid: 2*NE*8 + pad = 16 MB; total ~37.3 MB

    fuse_kernel<<<1, 128, 0, stream>>>(Wu, bu, Wm, bm, W1, b1, W2, Mt);
    bhist_kernel<<<SBLK, STHR, 0, stream>>>(ei + NE, H);
    bscan_kernel<<<1, 1024, 0, stream>>>(H);
    bscatter_kernel<<<SBLK, STHR, 0, stream>>>(ei, ew, H, mid);
    bdeg_y_kernel<<<NBUCK, BCOLS, 0, stream>>>(mid, H, ux, mx, dinv, y);
    bagg_mlp_kernel<<<NBUCK * 2, AGB, 0, stream>>>(mid, H, dinv, y, Mt, b2, smid, out);
}